// Round 2
// baseline (415.970 us; speedup 1.0000x reference)
//
#include <hip/hip_runtime.h>

// Problem constants (from reference)
#define BB 4
#define CC 256
#define XX 256
#define YY 256
#define NCELLS (BB * XX * YY)   // 262144 cells, 1 MiB of int32

#define TILE_Y 32               // cells per block
#define C_PAD  260              // 256 + 4 floats: rows stay 16B-aligned, breaks 32-bank stride

// ---------------------------------------------------------------------------
// Kernel 1: fill the cell->row index grid with -1 (int4-vectorized, coalesced)
// ---------------------------------------------------------------------------
__global__ void k_fill_idx(int4* __restrict__ idx4) {
    int i = blockIdx.x * blockDim.x + threadIdx.x;   // NCELLS/4 threads exactly
    idx4[i] = make_int4(-1, -1, -1, -1);
}

// ---------------------------------------------------------------------------
// Kernel 2: scatter row index n into idx[cell]  (coords unique => no races)
// ---------------------------------------------------------------------------
__global__ void k_scatter_idx(const int* __restrict__ coords,
                              int* __restrict__ idx, int n) {
    int i = blockIdx.x * blockDim.x + threadIdx.x;
    if (i >= n) return;
    int b = coords[i * 3 + 0];
    int x = coords[i * 3 + 1];
    int y = coords[i * 3 + 2];
    if ((unsigned)b < BB && (unsigned)x < XX && (unsigned)y < YY) {
        idx[(b * XX + x) * YY + y] = i;
    }
}

// ---------------------------------------------------------------------------
// Kernel 3: LDS-staged transpose gather.
// Block = (b, x, y-tile of 32 cells). Phase 1: each wave loads 8 whole rows,
// one row per instruction (64 lanes x float4 = 1 KiB CONTIGUOUS read — best
// possible HBM pattern; 8 loads in flight before first use). Phase 2: read
// tile transposed, store float4 along y (lanes 0..7 cover 128B contiguous).
// ---------------------------------------------------------------------------
__launch_bounds__(256)
__global__ void k_gather_out(const float4* __restrict__ feats4,
                             const int* __restrict__ idx,
                             float* __restrict__ out) {
    __shared__ float tile[TILE_Y][C_PAD];   // 32*260*4 = 33280 B -> 4 blocks/CU

    int blk = blockIdx.x;                   // 0 .. 8191
    int b   = blk >> 11;                    // /2048  (256 x * 8 ytiles)
    int x   = (blk >> 3) & 255;
    int y0  = (blk & 7) * TILE_Y;

    int t    = threadIdx.x;
    int lane = t & 63;
    int wv   = t >> 6;                      // wave 0..3

    int cellbase = (b * XX + x) * YY + y0;
    // every lane loads a copy of the 32 cell indices (lanes 0..31 hold them)
    int iv = idx[cellbase + (lane & 31)];

    // ---- phase 1: wave wv stages rows for cells wv*8 .. wv*8+7 ----
    int rows[8];
    #pragma unroll
    for (int j = 0; j < 8; ++j)
        rows[j] = __shfl(iv, wv * 8 + j);   // wave-uniform row index

    float4 v[8];
    #pragma unroll
    for (int j = 0; j < 8; ++j) {
        int r = rows[j];                    // wave-uniform branch, loads stay independent
        if (r >= 0) v[j] = feats4[(size_t)r * (CC / 4) + lane];  // 1 KiB contiguous/wave
        else        v[j] = make_float4(0.f, 0.f, 0.f, 0.f);
    }

    #pragma unroll
    for (int j = 0; j < 8; ++j) {
        int cell = wv * 8 + j;
        *(float4*)&tile[cell][lane * 4] = v[j];   // b128, rows 16B-aligned
    }
    __syncthreads();

    // ---- phase 2: transposed read, float4 stores along y ----
    int y4 = t & 7;                         // which group of 4 y within the 32
    int cp = t >> 3;                        // 0..31
    size_t outbase = ((size_t)b * CC) * (XX * YY) + (size_t)x * YY + y0 + y4 * 4;

    #pragma unroll
    for (int p = 0; p < 8; ++p) {
        int c = p * 32 + cp;
        float4 o;
        o.x = tile[y4 * 4 + 0][c];
        o.y = tile[y4 * 4 + 1][c];
        o.z = tile[y4 * 4 + 2][c];
        o.w = tile[y4 * 4 + 3][c];
        // lanes 0..7: same c, y-consecutive -> 128B contiguous per 8 lanes
        *(float4*)&out[outbase + (size_t)c * (XX * YY)] = o;
    }
}

extern "C" void kernel_launch(void* const* d_in, const int* in_sizes, int n_in,
                              void* d_out, int out_size, void* d_ws, size_t ws_size,
                              hipStream_t stream) {
    const float* feats  = (const float*)d_in[0];   // [N, 256] fp32
    const int*   coords = (const int*)d_in[1];     // [N, 3]   int32
    int n = in_sizes[1] / 3;                       // N = 200000

    int*   idx = (int*)d_ws;                       // 1 MiB scratch
    float* out = (float*)d_out;

    k_fill_idx<<<NCELLS / 4 / 256, 256, 0, stream>>>((int4*)idx);
    k_scatter_idx<<<(n + 255) / 256, 256, 0, stream>>>(coords, idx, n);
    k_gather_out<<<BB * XX * (YY / TILE_Y), 256, 0, stream>>>(
        (const float4*)feats, idx, out);
}